// Round 14
// baseline (865.318 us; speedup 1.0000x reference)
//
#include <hip/hip_runtime.h>
#include <hip/hip_bf16.h>
#include <math.h>

typedef __attribute__((ext_vector_type(8))) short short8;
typedef __attribute__((ext_vector_type(4))) float f32x4;
typedef __attribute__((ext_vector_type(4))) unsigned int u32x4;

#define KDIM 150528
#define KDIMB ((long)KDIM * 4)
#define NT_TILES 5
#define KCHUNKS 48
#define CHUNK_K 3136      // 150528 / 48
#define STEPS 196         // 3136 / 16
#define BK 16             // fp32 per step; MFMA consumes step-pairs (K=32)
#define HDIM 1280
#define MDIM 256
#define PSTRIDE (MDIM * HDIM)
#define BUFB 32768        // A 16KB [128 rows][128 B] + B 16KB
// LDS: 4 buffers * 32 KB = 128 KB -> 1 block/CU, 8 waves

// packed fp32x2 -> bf16x2 RNE, single HW instruction (no builtin on gfx950)
__device__ __forceinline__ unsigned int pk2(float a, float b) {
  unsigned int r;
  asm("v_cvt_pk_bf16_f32 %0, %1, %2" : "=v"(r) : "v"(a), "v"(b));
  return r;
}

// async global->LDS DMA, 16 B per lane, zero VGPR cost
__device__ __forceinline__ void gload16(const void* g, const char* l) {
  __builtin_amdgcn_global_load_lds(
      (const __attribute__((address_space(1))) unsigned int*)g,
      (__attribute__((address_space(3))) unsigned int*)l, 16, 0, 0);
}

__device__ __forceinline__ short8 cvt8(f32x4 lo, f32x4 hi) {
  union { u32x4 u; short8 s; } c;
  c.u = (u32x4){pk2(lo.x, lo.y), pk2(lo.z, lo.w), pk2(hi.x, hi.y), pk2(hi.z, hi.w)};
  return c.s;
}

// ---------------------------------------------------------------------------
// K1: split-K GEMM  P[kc][m][n] += X[m,k]*W[n,k], 256x256 tile, KCHUNKS=48.
// 512 thr (8 waves 4m x 2n, wave tile 64x128, acc[4][8]). fp32 DMA staging,
// 4 LDS bufs (idx = step&3), depth-2 STAGE(t+2), counted vmcnt(4), ONE raw
// s_barrier per step (R12 skeleton). MFMA on step-PAIRS: even buffer holds
// k0-15, odd k16-31; lane's 8-elem frag (k=(lane>>4)*8) is whole in one
// buffer -> lanes<32 read even, lanes>=32 odd (per-lane base select).
// LDS layout [rr=R&127][128B: h=R>>7 (64B) | 16 fp32] with slot-XOR
// (S ^ (rr&7) ^ buffer-parity); source pre-swizzled (rule #21).
// LDS/pair = 2300 cyc < HBM/pair = 3770 cyc -> HBM-bound at last.
// ---------------------------------------------------------------------------
__global__ __launch_bounds__(512, 2) void k_gemm(
    const float* __restrict__ X, const float* __restrict__ W,
    float* __restrict__ P) {
  extern __shared__ char smem[];
  // XCD-chunked swizzle (240 % 8 == 0): each XCD owns 6 kc x 5 nt blocks
  const int swz = (blockIdx.x & 7) * 30 + (blockIdx.x >> 3);
  const int kc = swz / 5;
  const int nt = swz % 5;
  const long k0b = (long)kc * CHUNK_K * 4;

  const int tid = threadIdx.x;
  const int lane = tid & 63;
  const int wv = tid >> 6;                  // 0..7 -> 4m x 2n wave grid
  const int wm = wv >> 1, wn = wv & 1;
  const int frow = lane & 15;
  const int s = lane >> 4;                  // k-slot 0..3 (8 elems each)
  const int shalf = s & 1;
  const int parb = lane >> 5;               // 0: even buf (k0-15), 1: odd

  // ---- staging source (pre-swizzled; derivation: LDS[rr][S] holds
  // G = S ^ (rr&7) ^ par; lane l of chunk c -> rr=8c+(l>>3), S=l&7;
  // (rr&7)=(l>>3)&7; G=h*4+kslot, R_glob=h*128+rr, col=kslot*16 ^ par*16)
  const int Gb = (lane & 7) ^ ((lane >> 3) & 7);
  const int dcol = (Gb & 1) ? -16 : 16;     // col toggle for odd-par steps
  const int rA0 = (Gb >> 2) * 128 + (wv * 2 + 0) * 8 + (lane >> 3);
  const int rA1 = (Gb >> 2) * 128 + (wv * 2 + 1) * 8 + (lane >> 3);
  const char* xA0 = (const char*)X + (long)rA0 * KDIMB + k0b + ((Gb & 3) << 4);
  const char* xA1 = (const char*)X + (long)rA1 * KDIMB + k0b + ((Gb & 3) << 4);
  const char* wB0 = (const char*)W + (long)(nt * 256 + rA0) * KDIMB + k0b + ((Gb & 3) << 4);
  const char* wB1 = (const char*)W + (long)(nt * 256 + rA1) * KDIMB + k0b + ((Gb & 3) << 4);

  // ---- frag read offsets (loop-invariant): R -> rr=R&127, S0=(R>>7)*4
  // + shalf*2; two b128 at slots (S0)^... and (S0+1)^..., XOR'd SEPARATELY
  int aoffl[4], aoffh[4], boffl[8], boffh[8];
#pragma unroll
  for (int i = 0; i < 4; ++i) {
    const int R = wm * 64 + i * 16 + frow;
    const int rr = R & 127;
    const int S0 = (R >> 7) * 4 + shalf * 2;
    aoffl[i] = rr * 128 + (((S0) ^ (rr & 7) ^ parb) << 4);
    aoffh[i] = rr * 128 + (((S0 + 1) ^ (rr & 7) ^ parb) << 4);
  }
#pragma unroll
  for (int j = 0; j < 8; ++j) {
    const int R = wn * 128 + j * 16 + frow;
    const int rr = R & 127;
    const int S0 = (R >> 7) * 4 + shalf * 2;
    boffl[j] = 16384 + rr * 128 + (((S0) ^ (rr & 7) ^ parb) << 4);
    boffh[j] = 16384 + rr * 128 + (((S0 + 1) ^ (rr & 7) ^ parb) << 4);
  }

  f32x4 acc[4][8];
#pragma unroll
  for (int i = 0; i < 4; ++i)
#pragma unroll
    for (int j = 0; j < 8; ++j) acc[i][j] = (f32x4){0.f, 0.f, 0.f, 0.f};

#define STAGE(bufp, ts)                                                       \
  {                                                                           \
    const long ko = (long)(ts) * 64 + (((ts) & 1) ? dcol : 0);                \
    gload16(xA0 + ko, (bufp) + (wv * 2 + 0) * 1024);                          \
    gload16(xA1 + ko, (bufp) + (wv * 2 + 1) * 1024);                          \
    gload16(wB0 + ko, (bufp) + 16384 + (wv * 2 + 0) * 1024);                  \
    gload16(wB1 + ko, (bufp) + 16384 + (wv * 2 + 1) * 1024);                  \
  }

  // prologue: steps 0,1 in flight (8 outstanding VMEM/wave)
  STAGE(smem, 0);
  STAGE(smem + BUFB, 1);

  for (int t = 0; t < STEPS; ++t) {
    // counted wait: outstanding {t, t+1} = 8 -> oldest 4 (batch t) landed
    asm volatile("s_waitcnt vmcnt(4)" ::: "memory");
    __builtin_amdgcn_s_barrier();
    __builtin_amdgcn_sched_barrier(0);
    // always stage (tail clamps source) -> vmcnt semantics stay uniform;
    // target buf held step t-2, consumed before this barrier: race-free
    const int ts = (t + 2 < STEPS) ? t + 2 : STEPS - 1;
    STAGE(smem + ((t + 2) & 3) * BUFB, ts);
    __builtin_amdgcn_sched_barrier(0);
    if (t & 1) {  // odd step: both pair-buffers resident -> compute K=32
      const char* bufE = smem + ((t - 1) & 3) * BUFB;
      const char* bufO = smem + (t & 3) * BUFB;
      const char* mb = (lane & 32) ? bufO : bufE;
      __builtin_amdgcn_s_setprio(1);
      short8 fa[4];
#pragma unroll
      for (int i = 0; i < 4; ++i) {
        const f32x4 lo = *(const f32x4*)(mb + aoffl[i]);
        const f32x4 hi = *(const f32x4*)(mb + aoffh[i]);
        fa[i] = cvt8(lo, hi);
      }
#pragma unroll
      for (int j = 0; j < 8; ++j) {
        const f32x4 lo = *(const f32x4*)(mb + boffl[j]);
        const f32x4 hi = *(const f32x4*)(mb + boffh[j]);
        const short8 fb = cvt8(lo, hi);
#pragma unroll
        for (int i = 0; i < 4; ++i)
          acc[i][j] = __builtin_amdgcn_mfma_f32_16x16x32_bf16(fa[i], fb,
                                                              acc[i][j], 0, 0, 0);
      }
      __builtin_amdgcn_s_setprio(0);
    }
  }
#undef STAGE

  // C/D layout: col=lane&15, row=(lane>>4)*4+r  [m89]
  float* Pc = P + (long)kc * PSTRIDE + nt * 256;
  const int rb = wm * 64 + ((lane >> 4) << 2);
  const int cb = wn * 128 + frow;
#pragma unroll
  for (int i = 0; i < 4; ++i)
#pragma unroll
    for (int j = 0; j < 8; ++j) {
      const int col = cb + j * 16;
#pragma unroll
      for (int r = 0; r < 4; ++r)
        Pc[(long)(rb + i * 16 + r) * HDIM + col] = acc[i][j][r];
    }
}

// ---------------------------------------------------------------------------
// K2: S4D kernel table, one thread per (h,l).
// ---------------------------------------------------------------------------
__global__ __launch_bounds__(256) void k_s4d(
    const float* __restrict__ log_dt, const float* __restrict__ lar,
    const float* __restrict__ C, float* __restrict__ ktab) {
  const int idx = blockIdx.x * 256 + threadIdx.x;  // 1280*64
  const int h = idx >> 6, l = idx & 63;
  const float dt = expf(log_dt[h]);
  const float fl = (float)l;
  float acc = 0.f;
#pragma unroll 4
  for (int n = 0; n < 32; ++n) {
    const float A = -expf(lar[h * 32 + n]);
    const float dtA = A * dt;
    const float Cb = C[h * 32 + n] * expm1f(dtA) / A;
    acc += Cb * expf(dtA * fl);
  }
  ktab[idx] = 2.f * acc;
}

// ---------------------------------------------------------------------------
// K3: split-K reduce  U[m][h] = bb[h] + sum_kc P  (full-chip parallel)
// ---------------------------------------------------------------------------
__global__ __launch_bounds__(256) void k_red(
    const float* __restrict__ P, const float* __restrict__ bb,
    float* __restrict__ U) {
  const int idx = blockIdx.x * 256 + threadIdx.x;  // 256*1280
  float s = bb[idx % HDIM];
#pragma unroll
  for (int c = 0; c < KCHUNKS; ++c) s += P[(long)c * PSTRIDE + idx];
  U[idx] = s;
}

// ---------------------------------------------------------------------------
// K4: causal conv at l=63 + D skip + exact GELU (reads tiny U)
// ---------------------------------------------------------------------------
__global__ __launch_bounds__(256) void k_conv(
    const float* __restrict__ U, const float* __restrict__ ktab,
    const float* __restrict__ Dv, float* __restrict__ y63) {
  __shared__ float kt[64 * 65];
  const int t = threadIdx.x;
  const int hw = blockIdx.x * 64;
  for (int i = t; i < 4096; i += 256)
    kt[(i >> 6) * 65 + (i & 63)] = ktab[(hw + (i >> 6)) * 64 + (i & 63)];
  __syncthreads();
  const int hl = t & 63, b = t >> 6;
  const int h = hw + hl;
  float y = 0.f;
  for (int m = 0; m < 64; ++m)
    y += U[(long)(b * 64 + m) * HDIM + h] * kt[hl * 65 + (63 - m)];
  y += Dv[h] * U[(long)(b * 64 + 63) * HDIM + h];
  y63[b * HDIM + h] = 0.5f * y * (1.f + erff(y * 0.70710678118654752f));
}

// ---------------------------------------------------------------------------
// K5: gating z=Wc@y63+bc, last = a*sigmoid(g). One wave per h-row.
// ---------------------------------------------------------------------------
__global__ __launch_bounds__(64) void k_gate(
    const float* __restrict__ y63, const float* __restrict__ Wc,
    const float* __restrict__ bc, float* __restrict__ lastv) {
  const int r = blockIdx.x;       // 0..1279
  const int l = threadIdx.x;      // 0..63
  const float* wa = Wc + (long)r * HDIM;
  const float* wg = Wc + (long)(HDIM + r) * HDIM;
  float sa[4] = {0.f, 0.f, 0.f, 0.f}, sg[4] = {0.f, 0.f, 0.f, 0.f};
#pragma unroll
  for (int seg = 0; seg < 5; ++seg) {
    const int j = seg * 256 + l * 4;
    const f32x4 a4 = *(const f32x4*)(wa + j);
    const f32x4 g4 = *(const f32x4*)(wg + j);
#pragma unroll
    for (int b = 0; b < 4; ++b) {
      const f32x4 yv = *(const f32x4*)(y63 + b * HDIM + j);
      sa[b] += a4.x * yv.x + a4.y * yv.y + a4.z * yv.z + a4.w * yv.w;
      sg[b] += g4.x * yv.x + g4.y * yv.y + g4.z * yv.z + g4.w * yv.w;
    }
  }
#pragma unroll
  for (int off = 32; off; off >>= 1)
#pragma unroll
    for (int b = 0; b < 4; ++b) {
      sa[b] += __shfl_down(sa[b], off);
      sg[b] += __shfl_down(sg[b], off);
    }
  if (l == 0) {
    const float ba = bc[r], bg = bc[HDIM + r];
#pragma unroll
    for (int b = 0; b < 4; ++b) {
      const float za = ba + sa[b], zg = bg + sg[b];
      lastv[b * HDIM + r] = za / (1.f + expf(-zg));
    }
  }
}

// ---------------------------------------------------------------------------
// K6: head  h1 = relu(last @ W1^T + b1); out = h1 @ W2^T + b2
// ---------------------------------------------------------------------------
__global__ __launch_bounds__(64) void k_head(
    const float* __restrict__ lastv, const float* __restrict__ W1,
    const float* __restrict__ b1, const float* __restrict__ W2,
    const float* __restrict__ b2, float* __restrict__ out) {
  __shared__ float ll[HDIM];
  __shared__ float h1[64];
  const int b = blockIdx.x, t = threadIdx.x;
  for (int i = t; i < HDIM; i += 64) ll[i] = lastv[b * HDIM + i];
  __syncthreads();
  {
    const float* w = W1 + t * HDIM;
    float s = b1[t];
    for (int j = 0; j < HDIM; j += 4) {
      const f32x4 wv = *(const f32x4*)(w + j);
      s += wv.x * ll[j] + wv.y * ll[j + 1] + wv.z * ll[j + 2] + wv.w * ll[j + 3];
    }
    h1[t] = fmaxf(s, 0.f);
  }
  __syncthreads();
  if (t < 60) {
    const float* w = W2 + t * 64;
    float o = b2[t];
#pragma unroll
    for (int r = 0; r < 64; ++r) o += w[r] * h1[r];
    out[b * 60 + t] = o;
  }
}

extern "C" void kernel_launch(void* const* d_in, const int* in_sizes, int n_in,
                              void* d_out, int out_size, void* d_ws, size_t ws_size,
                              hipStream_t stream) {
  const float* x   = (const float*)d_in[0];
  const float* Wb  = (const float*)d_in[1];
  const float* bb  = (const float*)d_in[2];
  const float* ldt = (const float*)d_in[3];
  const float* C   = (const float*)d_in[4];
  const float* lar = (const float*)d_in[5];
  const float* Dv  = (const float*)d_in[6];
  const float* Wc  = (const float*)d_in[7];
  const float* bc  = (const float*)d_in[8];
  const float* W1  = (const float*)d_in[9];
  const float* b1  = (const float*)d_in[10];
  const float* W2  = (const float*)d_in[11];
  const float* b2  = (const float*)d_in[12];
  float* out = (float*)d_out;

  float* P     = (float*)d_ws;                     // 48*256*1280 f32 = 63 MB
  float* ktab  = P + (long)KCHUNKS * PSTRIDE;      // 1280*64
  float* U     = ktab + HDIM * 64;                 // 256*1280
  float* y63   = U + PSTRIDE;                      // 4*1280
  float* lastv = y63 + 4 * HDIM;                   // 4*1280

  (void)hipFuncSetAttribute(reinterpret_cast<const void*>(k_gemm),
                            hipFuncAttributeMaxDynamicSharedMemorySize,
                            4 * BUFB);

  k_s4d<<<320, 256, 0, stream>>>(ldt, lar, C, ktab);
  k_gemm<<<NT_TILES * KCHUNKS, 512, 4 * BUFB, stream>>>(x, Wb, P);
  k_red<<<PSTRIDE / 256, 256, 0, stream>>>(P, bb, U);
  k_conv<<<20, 256, 0, stream>>>(U, ktab, Dv, y63);
  k_gate<<<HDIM, 64, 0, stream>>>(y63, Wc, bc, lastv);
  k_head<<<4, 64, 0, stream>>>(lastv, W1, b1, W2, b2, out);
}

// Round 15
// 862.335 us; speedup vs baseline: 1.0035x; 1.0035x over previous
//
#include <hip/hip_runtime.h>
#include <hip/hip_bf16.h>
#include <math.h>

typedef __attribute__((ext_vector_type(8))) short short8;
typedef __attribute__((ext_vector_type(4))) float f32x4;
typedef __attribute__((ext_vector_type(4))) unsigned int u32x4;

#define KDIM 150528
#define KDIMB ((long)KDIM * 4)
#define NT_TILES 5
#define KCHUNKS 48
#define CHUNK_K 3136      // 150528 / 48
#define STEPS 196         // 3136 / 16
#define BK 16             // fp32 per step; MFMA consumes step-pairs (K=32)
#define HDIM 1280
#define MDIM 256
#define PSTRIDE (MDIM * HDIM)
#define BUFB 32768        // A 16KB [128 rows][128 B] + B 16KB
// LDS: 4 buffers * 32 KB = 128 KB -> 1 block/CU, 8 waves

// packed fp32x2 -> bf16x2 RNE, single HW instruction (no builtin on gfx950)
__device__ __forceinline__ unsigned int pk2(float a, float b) {
  unsigned int r;
  asm("v_cvt_pk_bf16_f32 %0, %1, %2" : "=v"(r) : "v"(a), "v"(b));
  return r;
}

// async global->LDS DMA, 16 B per lane, zero VGPR cost
__device__ __forceinline__ void gload16(const void* g, const char* l) {
  __builtin_amdgcn_global_load_lds(
      (const __attribute__((address_space(1))) unsigned int*)g,
      (__attribute__((address_space(3))) unsigned int*)l, 16, 0, 0);
}

__device__ __forceinline__ short8 cvt8(f32x4 lo, f32x4 hi) {
  union { u32x4 u; short8 s; } c;
  c.u = (u32x4){pk2(lo.x, lo.y), pk2(lo.z, lo.w), pk2(hi.x, hi.y), pk2(hi.z, hi.w)};
  return c.s;
}

// ---------------------------------------------------------------------------
// K1: split-K GEMM  P[kc][m][n] += X[m,k]*W[n,k], 256x256 tile, KCHUNKS=48.
// 512 thr (8 waves 4m x 2n, wave tile 64x128, acc[4][8]). fp32 DMA staging,
// 4 LDS bufs (idx = step&3), depth-2 STAGE(t+2), counted vmcnt(4), ONE raw
// s_barrier per step (R12 skeleton). MFMA on step-PAIRS (even buf k0-15,
// odd k16-31; lane's frag whole in one buffer, per-lane base select).
// R15 FIX vs R14: __launch_bounds__(512,1). R14's (512,2) capped VGPR at
// 128 = acc alone -> ~1 GB scratch spill (WRITE_SIZE 1.05e9 vs 63 MB real).
// 256-VGPR budget fits acc(128)+frags(~70) with zero spill.
// ---------------------------------------------------------------------------
__global__ __launch_bounds__(512, 1) void k_gemm(
    const float* __restrict__ X, const float* __restrict__ W,
    float* __restrict__ P) {
  extern __shared__ char smem[];
  // XCD-chunked swizzle (240 % 8 == 0): each XCD owns 6 kc x 5 nt blocks
  const int swz = (blockIdx.x & 7) * 30 + (blockIdx.x >> 3);
  const int kc = swz / 5;
  const int nt = swz % 5;
  const long k0b = (long)kc * CHUNK_K * 4;

  const int tid = threadIdx.x;
  const int lane = tid & 63;
  const int wv = tid >> 6;                  // 0..7 -> 4m x 2n wave grid
  const int wm = wv >> 1, wn = wv & 1;
  const int frow = lane & 15;
  const int s = lane >> 4;                  // k-slot 0..3 (8 elems each)
  const int shalf = s & 1;
  const int parb = lane >> 5;               // 0: even buf (k0-15), 1: odd

  // ---- staging source (pre-swizzled; LDS[rr][S] holds G = S ^ (rr&7) ^ par)
  const int Gb = (lane & 7) ^ ((lane >> 3) & 7);
  const int dcol = (Gb & 1) ? -16 : 16;     // col toggle for odd-par steps
  const int rA0 = (Gb >> 2) * 128 + (wv * 2 + 0) * 8 + (lane >> 3);
  const int rA1 = (Gb >> 2) * 128 + (wv * 2 + 1) * 8 + (lane >> 3);
  const char* xA0 = (const char*)X + (long)rA0 * KDIMB + k0b + ((Gb & 3) << 4);
  const char* xA1 = (const char*)X + (long)rA1 * KDIMB + k0b + ((Gb & 3) << 4);
  const char* wB0 = (const char*)W + (long)(nt * 256 + rA0) * KDIMB + k0b + ((Gb & 3) << 4);
  const char* wB1 = (const char*)W + (long)(nt * 256 + rA1) * KDIMB + k0b + ((Gb & 3) << 4);

  // ---- frag read offsets (loop-invariant), lo/hi XOR'd SEPARATELY
  int aoffl[4], aoffh[4], boffl[8], boffh[8];
#pragma unroll
  for (int i = 0; i < 4; ++i) {
    const int R = wm * 64 + i * 16 + frow;
    const int rr = R & 127;
    const int S0 = (R >> 7) * 4 + shalf * 2;
    aoffl[i] = rr * 128 + (((S0) ^ (rr & 7) ^ parb) << 4);
    aoffh[i] = rr * 128 + (((S0 + 1) ^ (rr & 7) ^ parb) << 4);
  }
#pragma unroll
  for (int j = 0; j < 8; ++j) {
    const int R = wn * 128 + j * 16 + frow;
    const int rr = R & 127;
    const int S0 = (R >> 7) * 4 + shalf * 2;
    boffl[j] = 16384 + rr * 128 + (((S0) ^ (rr & 7) ^ parb) << 4);
    boffh[j] = 16384 + rr * 128 + (((S0 + 1) ^ (rr & 7) ^ parb) << 4);
  }

  f32x4 acc[4][8];
#pragma unroll
  for (int i = 0; i < 4; ++i)
#pragma unroll
    for (int j = 0; j < 8; ++j) acc[i][j] = (f32x4){0.f, 0.f, 0.f, 0.f};

#define STAGE(bufp, ts)                                                       \
  {                                                                           \
    const long ko = (long)(ts) * 64 + (((ts) & 1) ? dcol : 0);                \
    gload16(xA0 + ko, (bufp) + (wv * 2 + 0) * 1024);                          \
    gload16(xA1 + ko, (bufp) + (wv * 2 + 1) * 1024);                          \
    gload16(wB0 + ko, (bufp) + 16384 + (wv * 2 + 0) * 1024);                  \
    gload16(wB1 + ko, (bufp) + 16384 + (wv * 2 + 1) * 1024);                  \
  }

  // prologue: steps 0,1 in flight (8 outstanding VMEM/wave)
  STAGE(smem, 0);
  STAGE(smem + BUFB, 1);

  for (int t = 0; t < STEPS; ++t) {
    // counted wait: outstanding {t, t+1} = 8 -> oldest 4 (batch t) landed
    asm volatile("s_waitcnt vmcnt(4)" ::: "memory");
    __builtin_amdgcn_s_barrier();
    __builtin_amdgcn_sched_barrier(0);
    // always stage (tail clamps source) -> vmcnt semantics stay uniform;
    // target buf held step t-2, consumed before this barrier: race-free
    const int ts = (t + 2 < STEPS) ? t + 2 : STEPS - 1;
    STAGE(smem + ((t + 2) & 3) * BUFB, ts);
    __builtin_amdgcn_sched_barrier(0);
    if (t & 1) {  // odd step: both pair-buffers resident -> compute K=32
      const char* bufE = smem + ((t - 1) & 3) * BUFB;
      const char* bufO = smem + (t & 3) * BUFB;
      const char* mb = (lane & 32) ? bufO : bufE;
      __builtin_amdgcn_s_setprio(1);
      short8 fa[4];
#pragma unroll
      for (int i = 0; i < 4; ++i) {
        const f32x4 lo = *(const f32x4*)(mb + aoffl[i]);
        const f32x4 hi = *(const f32x4*)(mb + aoffh[i]);
        fa[i] = cvt8(lo, hi);
      }
#pragma unroll
      for (int j = 0; j < 8; ++j) {
        const f32x4 lo = *(const f32x4*)(mb + boffl[j]);
        const f32x4 hi = *(const f32x4*)(mb + boffh[j]);
        const short8 fb = cvt8(lo, hi);
#pragma unroll
        for (int i = 0; i < 4; ++i)
          acc[i][j] = __builtin_amdgcn_mfma_f32_16x16x32_bf16(fa[i], fb,
                                                              acc[i][j], 0, 0, 0);
      }
      __builtin_amdgcn_s_setprio(0);
    }
  }
#undef STAGE

  // C/D layout: col=lane&15, row=(lane>>4)*4+r  [m89]
  float* Pc = P + (long)kc * PSTRIDE + nt * 256;
  const int rb = wm * 64 + ((lane >> 4) << 2);
  const int cb = wn * 128 + frow;
#pragma unroll
  for (int i = 0; i < 4; ++i)
#pragma unroll
    for (int j = 0; j < 8; ++j) {
      const int col = cb + j * 16;
#pragma unroll
      for (int r = 0; r < 4; ++r)
        Pc[(long)(rb + i * 16 + r) * HDIM + col] = acc[i][j][r];
    }
}

// ---------------------------------------------------------------------------
// K2: S4D kernel table, one thread per (h,l).
// ---------------------------------------------------------------------------
__global__ __launch_bounds__(256) void k_s4d(
    const float* __restrict__ log_dt, const float* __restrict__ lar,
    const float* __restrict__ C, float* __restrict__ ktab) {
  const int idx = blockIdx.x * 256 + threadIdx.x;  // 1280*64
  const int h = idx >> 6, l = idx & 63;
  const float dt = expf(log_dt[h]);
  const float fl = (float)l;
  float acc = 0.f;
#pragma unroll 4
  for (int n = 0; n < 32; ++n) {
    const float A = -expf(lar[h * 32 + n]);
    const float dtA = A * dt;
    const float Cb = C[h * 32 + n] * expm1f(dtA) / A;
    acc += Cb * expf(dtA * fl);
  }
  ktab[idx] = 2.f * acc;
}

// ---------------------------------------------------------------------------
// K3: split-K reduce  U[m][h] = bb[h] + sum_kc P  (full-chip parallel)
// ---------------------------------------------------------------------------
__global__ __launch_bounds__(256) void k_red(
    const float* __restrict__ P, const float* __restrict__ bb,
    float* __restrict__ U) {
  const int idx = blockIdx.x * 256 + threadIdx.x;  // 256*1280
  float s = bb[idx % HDIM];
#pragma unroll
  for (int c = 0; c < KCHUNKS; ++c) s += P[(long)c * PSTRIDE + idx];
  U[idx] = s;
}

// ---------------------------------------------------------------------------
// K4: causal conv at l=63 + D skip + exact GELU (reads tiny U)
// ---------------------------------------------------------------------------
__global__ __launch_bounds__(256) void k_conv(
    const float* __restrict__ U, const float* __restrict__ ktab,
    const float* __restrict__ Dv, float* __restrict__ y63) {
  __shared__ float kt[64 * 65];
  const int t = threadIdx.x;
  const int hw = blockIdx.x * 64;
  for (int i = t; i < 4096; i += 256)
    kt[(i >> 6) * 65 + (i & 63)] = ktab[(hw + (i >> 6)) * 64 + (i & 63)];
  __syncthreads();
  const int hl = t & 63, b = t >> 6;
  const int h = hw + hl;
  float y = 0.f;
  for (int m = 0; m < 64; ++m)
    y += U[(long)(b * 64 + m) * HDIM + h] * kt[hl * 65 + (63 - m)];
  y += Dv[h] * U[(long)(b * 64 + 63) * HDIM + h];
  y63[b * HDIM + h] = 0.5f * y * (1.f + erff(y * 0.70710678118654752f));
}

// ---------------------------------------------------------------------------
// K5: gating z=Wc@y63+bc, last = a*sigmoid(g). One wave per h-row.
// ---------------------------------------------------------------------------
__global__ __launch_bounds__(64) void k_gate(
    const float* __restrict__ y63, const float* __restrict__ Wc,
    const float* __restrict__ bc, float* __restrict__ lastv) {
  const int r = blockIdx.x;       // 0..1279
  const int l = threadIdx.x;      // 0..63
  const float* wa = Wc + (long)r * HDIM;
  const float* wg = Wc + (long)(HDIM + r) * HDIM;
  float sa[4] = {0.f, 0.f, 0.f, 0.f}, sg[4] = {0.f, 0.f, 0.f, 0.f};
#pragma unroll
  for (int seg = 0; seg < 5; ++seg) {
    const int j = seg * 256 + l * 4;
    const f32x4 a4 = *(const f32x4*)(wa + j);
    const f32x4 g4 = *(const f32x4*)(wg + j);
#pragma unroll
    for (int b = 0; b < 4; ++b) {
      const f32x4 yv = *(const f32x4*)(y63 + b * HDIM + j);
      sa[b] += a4.x * yv.x + a4.y * yv.y + a4.z * yv.z + a4.w * yv.w;
      sg[b] += g4.x * yv.x + g4.y * yv.y + g4.z * yv.z + g4.w * yv.w;
    }
  }
#pragma unroll
  for (int off = 32; off; off >>= 1)
#pragma unroll
    for (int b = 0; b < 4; ++b) {
      sa[b] += __shfl_down(sa[b], off);
      sg[b] += __shfl_down(sg[b], off);
    }
  if (l == 0) {
    const float ba = bc[r], bg = bc[HDIM + r];
#pragma unroll
    for (int b = 0; b < 4; ++b) {
      const float za = ba + sa[b], zg = bg + sg[b];
      lastv[b * HDIM + r] = za / (1.f + expf(-zg));
    }
  }
}

// ---------------------------------------------------------------------------
// K6: head  h1 = relu(last @ W1^T + b1); out = h1 @ W2^T + b2
// ---------------------------------------------------------------------------
__global__ __launch_bounds__(64) void k_head(
    const float* __restrict__ lastv, const float* __restrict__ W1,
    const float* __restrict__ b1, const float* __restrict__ W2,
    const float* __restrict__ b2, float* __restrict__ out) {
  __shared__ float ll[HDIM];
  __shared__ float h1[64];
  const int b = blockIdx.x, t = threadIdx.x;
  for (int i = t; i < HDIM; i += 64) ll[i] = lastv[b * HDIM + i];
  __syncthreads();
  {
    const float* w = W1 + t * HDIM;
    float s = b1[t];
    for (int j = 0; j < HDIM; j += 4) {
      const f32x4 wv = *(const f32x4*)(w + j);
      s += wv.x * ll[j] + wv.y * ll[j + 1] + wv.z * ll[j + 2] + wv.w * ll[j + 3];
    }
    h1[t] = fmaxf(s, 0.f);
  }
  __syncthreads();
  if (t < 60) {
    const float* w = W2 + t * 64;
    float o = b2[t];
#pragma unroll
    for (int r = 0; r < 64; ++r) o += w[r] * h1[r];
    out[b * 60 + t] = o;
  }
}

extern "C" void kernel_launch(void* const* d_in, const int* in_sizes, int n_in,
                              void* d_out, int out_size, void* d_ws, size_t ws_size,
                              hipStream_t stream) {
  const float* x   = (const float*)d_in[0];
  const float* Wb  = (const float*)d_in[1];
  const float* bb  = (const float*)d_in[2];
  const float* ldt = (const float*)d_in[3];
  const float* C   = (const float*)d_in[4];
  const float* lar = (const float*)d_in[5];
  const float* Dv  = (const float*)d_in[6];
  const float* Wc  = (const float*)d_in[7];
  const float* bc  = (const float*)d_in[8];
  const float* W1  = (const float*)d_in[9];
  const float* b1  = (const float*)d_in[10];
  const float* W2  = (const float*)d_in[11];
  const float* b2  = (const float*)d_in[12];
  float* out = (float*)d_out;

  float* P     = (float*)d_ws;                     // 48*256*1280 f32 = 63 MB
  float* ktab  = P + (long)KCHUNKS * PSTRIDE;      // 1280*64
  float* U     = ktab + HDIM * 64;                 // 256*1280
  float* y63   = U + PSTRIDE;                      // 4*1280
  float* lastv = y63 + 4 * HDIM;                   // 4*1280

  (void)hipFuncSetAttribute(reinterpret_cast<const void*>(k_gemm),
                            hipFuncAttributeMaxDynamicSharedMemorySize,
                            4 * BUFB);

  k_s4d<<<320, 256, 0, stream>>>(ldt, lar, C, ktab);
  k_gemm<<<NT_TILES * KCHUNKS, 512, 4 * BUFB, stream>>>(x, Wb, P);
  k_red<<<PSTRIDE / 256, 256, 0, stream>>>(P, bb, U);
  k_conv<<<20, 256, 0, stream>>>(U, ktab, Dv, y63);
  k_gate<<<HDIM, 64, 0, stream>>>(y63, Wc, bc, lastv);
  k_head<<<4, 64, 0, stream>>>(lastv, W1, b1, W2, b2, out);
}

// Round 16
// 369.015 us; speedup vs baseline: 2.3449x; 2.3369x over previous
//
#include <hip/hip_runtime.h>
#include <hip/hip_bf16.h>
#include <math.h>

typedef __attribute__((ext_vector_type(8))) short short8;
typedef __attribute__((ext_vector_type(4))) float f32x4;
typedef __attribute__((ext_vector_type(4))) unsigned int u32x4;

#define KDIM 150528
#define NT_TILES 10
#define MT_TILES 2
#define KCHUNKS 24
#define CHUNK_K 6272
#define STEPS 196         // 6272 / 32
#define BK 32
#define HDIM 1280
#define MDIM 256
#define PSTRIDE (MDIM * HDIM)
#define AREG 10240        // A: 128 rows * 80 B (padded bf16)
#define BUFB 20480        // + B: 128 rows * 80 B
// LDS: 3 buffers * 20 KB = 60 KB -> 2 blocks/CU

// packed fp32x2 -> bf16x2 RNE, single HW instruction (no builtin on gfx950)
__device__ __forceinline__ unsigned int pk2(float a, float b) {
  unsigned int r;
  asm("v_cvt_pk_bf16_f32 %0, %1, %2" : "=v"(r) : "v"(a), "v"(b));
  return r;
}
__device__ __forceinline__ u32x4 pk8(f32x4 a, f32x4 b) {
  return (u32x4){pk2(a.x, a.y), pk2(a.z, a.w), pk2(b.x, b.y), pk2(b.z, b.w)};
}

// ---------------------------------------------------------------------------
// K1: split-K GEMM, PRODUCER/CONSUMER wave specialization.
// Tile 128x128, BK=32, 512 thr. Waves 0-3: consumers (ds_read bf16 frags +
// 16 MFMA each, acc[4][4]=64 VGPR, no global loads). Waves 4-7: producers
// (8x f32x4 global load -> cvt_pk -> 4x ds_write_b128 bf16; no acc, ~50
// VGPR). Both paths fit the 128-VGPR cap that killed R14/R15 (1 GB spill).
// bf16 LDS halves frag-read bytes vs R12's fp32 (96 vs 176 KB/CU/step).
// 3 rotating buffers, RAW barriers only — producer global loads stay in
// flight across barriers in registers; vmcnt never drains. 80 B-padded rows:
// frag reads 2-way bank (free), writes <=4-way. 2 blocks/CU; producer and
// consumer waves co-schedule per SIMD (m114 MFMA||VMEM overlap).
// Race: phase t, consumers read buf[t%3], producers write buf[(t+1)%3].
// ---------------------------------------------------------------------------
__global__ __launch_bounds__(512, 2) void k_gemm(
    const float* __restrict__ X, const float* __restrict__ W,
    float* __restrict__ P) {
  extern __shared__ char smem[];
  // XCD-chunked swizzle (480 % 8 == 0); mt-pairs adjacent -> share W via L2
  const int swz = (blockIdx.x & 7) * 60 + (blockIdx.x >> 3);
  const int kc = swz / 20;
  const int rem = swz % 20;
  const int nt = rem >> 1;
  const int mt = rem & 1;
  const long k0 = (long)kc * CHUNK_K;

  const int tid = threadIdx.x;
  const int lane = tid & 63;
  const int wv = tid >> 6;

  if (wv >= 4) {
    // ================= PRODUCER =================
    const int r = (wv - 4) * 32 + (lane >> 1);   // 0..127
    const int h = lane & 1;                      // fp32 half (16 of 32)
    const float* ga = X + (long)(mt * 128 + r) * KDIM + k0 + h * 16;
    const float* gb = W + (long)(nt * 128 + r) * KDIM + k0 + h * 16;
    const int wa = r * 80 + h * 32;
    const int wb = AREG + r * 80 + h * 32;
    f32x4 a0, a1, a2, a3, b0, b1, b2, b3;
#define LOADP(t)                                                              \
  {                                                                           \
    const long o = (long)(t) * BK;                                            \
    a0 = *(const f32x4*)(ga + o);      a1 = *(const f32x4*)(ga + o + 4);      \
    a2 = *(const f32x4*)(ga + o + 8);  a3 = *(const f32x4*)(ga + o + 12);     \
    b0 = *(const f32x4*)(gb + o);      b1 = *(const f32x4*)(gb + o + 4);      \
    b2 = *(const f32x4*)(gb + o + 8);  b3 = *(const f32x4*)(gb + o + 12);     \
  }
#define CVTW(buf)                                                             \
  {                                                                           \
    *(u32x4*)((buf) + wa) = pk8(a0, a1);                                      \
    *(u32x4*)((buf) + wa + 16) = pk8(a2, a3);                                 \
    *(u32x4*)((buf) + wb) = pk8(b0, b1);                                      \
    *(u32x4*)((buf) + wb + 16) = pk8(b2, b3);                                 \
  }
    LOADP(0);
    CVTW(smem);                        // buf0 <- step 0
    LOADP(1);                          // regs hold step 1
    asm volatile("s_waitcnt lgkmcnt(0)" ::: "memory");
    __builtin_amdgcn_s_barrier();
    int nb = 1;                        // (t+1)%3 rotating
    for (int t = 0; t < STEPS; ++t) {
      if (t + 1 < STEPS) CVTW(smem + nb * BUFB);   // regs(t+1) -> buf
      if (t + 2 < STEPS) LOADP(t + 2);             // refill regs
      __builtin_amdgcn_sched_barrier(0);
      asm volatile("s_waitcnt lgkmcnt(0)" ::: "memory");  // ds_writes visible
      __builtin_amdgcn_s_barrier();
      nb = (nb == 2) ? 0 : nb + 1;
    }
#undef LOADP
#undef CVTW
  } else {
    // ================= CONSUMER =================
    const int wm = wv >> 1, wn = wv & 1;
    const int frow = lane & 15;
    const int fsl = (lane >> 4) << 4;  // 16B slot = 8 bf16 k-group
    int aoff[4], boff[4];
#pragma unroll
    for (int i = 0; i < 4; ++i) {
      aoff[i] = (wm * 64 + i * 16 + frow) * 80 + fsl;
      boff[i] = AREG + (wn * 64 + i * 16 + frow) * 80 + fsl;
    }
    f32x4 acc[4][4];
#pragma unroll
    for (int i = 0; i < 4; ++i)
#pragma unroll
      for (int j = 0; j < 4; ++j) acc[i][j] = (f32x4){0.f, 0.f, 0.f, 0.f};

    __builtin_amdgcn_s_barrier();      // match producer prologue barrier
    int cb = 0;                        // t%3 rotating
    for (int t = 0; t < STEPS; ++t) {
      const char* bf = smem + cb * BUFB;
      __builtin_amdgcn_s_setprio(1);
      short8 fa[4];
#pragma unroll
      for (int i = 0; i < 4; ++i) fa[i] = *(const short8*)(bf + aoff[i]);
#pragma unroll
      for (int j = 0; j < 4; ++j) {
        const short8 fb = *(const short8*)(bf + boff[j]);
#pragma unroll
        for (int i = 0; i < 4; ++i)
          acc[i][j] = __builtin_amdgcn_mfma_f32_16x16x32_bf16(fa[i], fb,
                                                              acc[i][j], 0, 0, 0);
      }
      __builtin_amdgcn_s_setprio(0);
      __builtin_amdgcn_s_barrier();    // end of phase t
      cb = (cb == 2) ? 0 : cb + 1;
    }
    // C/D layout: col=lane&15, row=(lane>>4)*4+r  [m89]
    float* Pc = P + (long)kc * PSTRIDE + (long)mt * 128 * HDIM + nt * 128;
    const int rb = wm * 64 + ((lane >> 4) << 2);
    const int cbase = wn * 64 + frow;
#pragma unroll
    for (int i = 0; i < 4; ++i)
#pragma unroll
      for (int j = 0; j < 4; ++j) {
        const int col = cbase + j * 16;
#pragma unroll
        for (int r = 0; r < 4; ++r)
          Pc[(long)(rb + i * 16 + r) * HDIM + col] = acc[i][j][r];
      }
  }
}

// ---------------------------------------------------------------------------
// K2: S4D kernel table, one thread per (h,l).
// ---------------------------------------------------------------------------
__global__ __launch_bounds__(256) void k_s4d(
    const float* __restrict__ log_dt, const float* __restrict__ lar,
    const float* __restrict__ C, float* __restrict__ ktab) {
  const int idx = blockIdx.x * 256 + threadIdx.x;  // 1280*64
  const int h = idx >> 6, l = idx & 63;
  const float dt = expf(log_dt[h]);
  const float fl = (float)l;
  float acc = 0.f;
#pragma unroll 4
  for (int n = 0; n < 32; ++n) {
    const float A = -expf(lar[h * 32 + n]);
    const float dtA = A * dt;
    const float Cb = C[h * 32 + n] * expm1f(dtA) / A;
    acc += Cb * expf(dtA * fl);
  }
  ktab[idx] = 2.f * acc;
}

// ---------------------------------------------------------------------------
// K3: split-K reduce  U[m][h] = bb[h] + sum_kc P  (full-chip parallel)
// ---------------------------------------------------------------------------
__global__ __launch_bounds__(256) void k_red(
    const float* __restrict__ P, const float* __restrict__ bb,
    float* __restrict__ U) {
  const int idx = blockIdx.x * 256 + threadIdx.x;  // 256*1280
  float s = bb[idx % HDIM];
#pragma unroll
  for (int c = 0; c < KCHUNKS; ++c) s += P[(long)c * PSTRIDE + idx];
  U[idx] = s;
}

// ---------------------------------------------------------------------------
// K4: causal conv at l=63 + D skip + exact GELU (reads tiny U)
// ---------------------------------------------------------------------------
__global__ __launch_bounds__(256) void k_conv(
    const float* __restrict__ U, const float* __restrict__ ktab,
    const float* __restrict__ Dv, float* __restrict__ y63) {
  __shared__ float kt[64 * 65];
  const int t = threadIdx.x;
  const int hw = blockIdx.x * 64;
  for (int i = t; i < 4096; i += 256)
    kt[(i >> 6) * 65 + (i & 63)] = ktab[(hw + (i >> 6)) * 64 + (i & 63)];
  __syncthreads();
  const int hl = t & 63, b = t >> 6;
  const int h = hw + hl;
  float y = 0.f;
  for (int m = 0; m < 64; ++m)
    y += U[(long)(b * 64 + m) * HDIM + h] * kt[hl * 65 + (63 - m)];
  y += Dv[h] * U[(long)(b * 64 + 63) * HDIM + h];
  y63[b * HDIM + h] = 0.5f * y * (1.f + erff(y * 0.70710678118654752f));
}

// ---------------------------------------------------------------------------
// K5: gating z=Wc@y63+bc, last = a*sigmoid(g). One wave per h-row.
// ---------------------------------------------------------------------------
__global__ __launch_bounds__(64) void k_gate(
    const float* __restrict__ y63, const float* __restrict__ Wc,
    const float* __restrict__ bc, float* __restrict__ lastv) {
  const int r = blockIdx.x;       // 0..1279
  const int l = threadIdx.x;      // 0..63
  const float* wa = Wc + (long)r * HDIM;
  const float* wg = Wc + (long)(HDIM + r) * HDIM;
  float sa[4] = {0.f, 0.f, 0.f, 0.f}, sg[4] = {0.f, 0.f, 0.f, 0.f};
#pragma unroll
  for (int seg = 0; seg < 5; ++seg) {
    const int j = seg * 256 + l * 4;
    const f32x4 a4 = *(const f32x4*)(wa + j);
    const f32x4 g4 = *(const f32x4*)(wg + j);
#pragma unroll
    for (int b = 0; b < 4; ++b) {
      const f32x4 yv = *(const f32x4*)(y63 + b * HDIM + j);
      sa[b] += a4.x * yv.x + a4.y * yv.y + a4.z * yv.z + a4.w * yv.w;
      sg[b] += g4.x * yv.x + g4.y * yv.y + g4.z * yv.z + g4.w * yv.w;
    }
  }
#pragma unroll
  for (int off = 32; off; off >>= 1)
#pragma unroll
    for (int b = 0; b < 4; ++b) {
      sa[b] += __shfl_down(sa[b], off);
      sg[b] += __shfl_down(sg[b], off);
    }
  if (l == 0) {
    const float ba = bc[r], bg = bc[HDIM + r];
#pragma unroll
    for (int b = 0; b < 4; ++b) {
      const float za = ba + sa[b], zg = bg + sg[b];
      lastv[b * HDIM + r] = za / (1.f + expf(-zg));
    }
  }
}

// ---------------------------------------------------------------------------
// K6: head  h1 = relu(last @ W1^T + b1); out = h1 @ W2^T + b2
// ---------------------------------------------------------------------------
__global__ __launch_bounds__(64) void k_head(
    const float* __restrict__ lastv, const float* __restrict__ W1,
    const float* __restrict__ b1, const float* __restrict__ W2,
    const float* __restrict__ b2, float* __restrict__ out) {
  __shared__ float ll[HDIM];
  __shared__ float h1[64];
  const int b = blockIdx.x, t = threadIdx.x;
  for (int i = t; i < HDIM; i += 64) ll[i] = lastv[b * HDIM + i];
  __syncthreads();
  {
    const float* w = W1 + t * HDIM;
    float s = b1[t];
    for (int j = 0; j < HDIM; j += 4) {
      const f32x4 wv = *(const f32x4*)(w + j);
      s += wv.x * ll[j] + wv.y * ll[j + 1] + wv.z * ll[j + 2] + wv.w * ll[j + 3];
    }
    h1[t] = fmaxf(s, 0.f);
  }
  __syncthreads();
  if (t < 60) {
    const float* w = W2 + t * 64;
    float o = b2[t];
#pragma unroll
    for (int r = 0; r < 64; ++r) o += w[r] * h1[r];
    out[b * 60 + t] = o;
  }
}

extern "C" void kernel_launch(void* const* d_in, const int* in_sizes, int n_in,
                              void* d_out, int out_size, void* d_ws, size_t ws_size,
                              hipStream_t stream) {
  const float* x   = (const float*)d_in[0];
  const float* Wb  = (const float*)d_in[1];
  const float* bb  = (const float*)d_in[2];
  const float* ldt = (const float*)d_in[3];
  const float* C   = (const float*)d_in[4];
  const float* lar = (const float*)d_in[5];
  const float* Dv  = (const float*)d_in[6];
  const float* Wc  = (const float*)d_in[7];
  const float* bc  = (const float*)d_in[8];
  const float* W1  = (const float*)d_in[9];
  const float* b1  = (const float*)d_in[10];
  const float* W2  = (const float*)d_in[11];
  const float* b2  = (const float*)d_in[12];
  float* out = (float*)d_out;

  float* P     = (float*)d_ws;                     // 24*256*1280 f32 = 31.5 MB
  float* ktab  = P + (long)KCHUNKS * PSTRIDE;      // 1280*64
  float* U     = ktab + HDIM * 64;                 // 256*1280
  float* y63   = U + PSTRIDE;                      // 4*1280
  float* lastv = y63 + 4 * HDIM;                   // 4*1280

  (void)hipFuncSetAttribute(reinterpret_cast<const void*>(k_gemm),
                            hipFuncAttributeMaxDynamicSharedMemorySize,
                            3 * BUFB);

  k_s4d<<<320, 256, 0, stream>>>(ldt, lar, C, ktab);
  k_gemm<<<NT_TILES * MT_TILES * KCHUNKS, 512, 3 * BUFB, stream>>>(x, Wb, P);
  k_red<<<PSTRIDE / 256, 256, 0, stream>>>(P, bb, U);
  k_conv<<<20, 256, 0, stream>>>(U, ktab, Dv, y63);
  k_gate<<<HDIM, 64, 0, stream>>>(y63, Wc, bc, lastv);
  k_head<<<4, 64, 0, stream>>>(lastv, W1, b1, W2, b2, out);
}

// Round 17
// 344.755 us; speedup vs baseline: 2.5100x; 1.0704x over previous
//
#include <hip/hip_runtime.h>
#include <hip/hip_bf16.h>
#include <math.h>

typedef __attribute__((ext_vector_type(8))) short short8;
typedef __attribute__((ext_vector_type(4))) float f32x4;
typedef __attribute__((ext_vector_type(4))) unsigned int u32x4;

#define KDIM 150528
#define KDIMB ((long)KDIM * 4)
#define NT_TILES 10
#define MT_TILES 2
#define KCHUNKS 24
#define STEPS 196         // 6272 / 32
#define BK 32             // fp32 -> 128 B LDS rows
#define HDIM 1280
#define MDIM 256
#define PSTRIDE (MDIM * HDIM)
#define ABYTES 16384      // A: 128 rows * 128 B
#define BUFB 32768        // + B: 128 rows * 128 B
// LDS: 2 buffers * 32 KB = 64 KB -> 2 blocks/CU. Independent barrier phases
// of the two blocks cover each other's step-boundary HBM bubbles.

// packed fp32x2 -> bf16x2 RNE, single HW instruction (no builtin on gfx950)
__device__ __forceinline__ unsigned int pk2(float a, float b) {
  unsigned int r;
  asm("v_cvt_pk_bf16_f32 %0, %1, %2" : "=v"(r) : "v"(a), "v"(b));
  return r;
}

// async global->LDS DMA, 16 B per lane, zero VGPR cost
__device__ __forceinline__ void gload16(const void* g, const char* l) {
  __builtin_amdgcn_global_load_lds(
      (const __attribute__((address_space(1))) unsigned int*)g,
      (__attribute__((address_space(3))) unsigned int*)l, 16, 0, 0);
}

__device__ __forceinline__ short8 cvt8(f32x4 lo, f32x4 hi) {
  union { u32x4 u; short8 s; } c;
  c.u = (u32x4){pk2(lo.x, lo.y), pk2(lo.z, lo.w), pk2(hi.x, hi.y), pk2(hi.z, hi.w)};
  return c.s;
}

// ---------------------------------------------------------------------------
// K1: split-K GEMM  P[kc][m][n] += X[m,k]*W[n,k] over k-chunk kc.
// Tile 128x128, BK=32, 256 thr (4 waves 2m x 2n, wave tile 64x64, acc 4x4).
// R12's proven loop discipline (fp32 DMA staging, raw barrier, vmcnt wait
// BEFORE barrier, STAGE issued right after) re-cut to 2 bufs / 64 KB so TWO
// blocks share each CU. R12 was fully serialized within its step (sum of
// LDS+cvt+MFMA = 3000 cyc ~ observed 3250); the sibling block's independent
// phase provides the overlap lockstep barriers forbid.
// NO mid-step lgkmcnt(0)/second barrier (R13's killer). Depth-1 is safe:
// loads issued at top of step t land during step t, awaited at top of t+1.
// ---------------------------------------------------------------------------
__global__ __launch_bounds__(256, 2) void k_gemm(
    const float* __restrict__ X, const float* __restrict__ W,
    float* __restrict__ P) {
  extern __shared__ char smem[];
  // XCD-chunked swizzle (480 % 8 == 0): chunk 60 = 3 kc x 10 nt x 2 mt;
  // mt-pairs adjacent -> the 2 sharers of a W panel co-run on one XCD's L2.
  const int swz = (blockIdx.x & 7) * 60 + (blockIdx.x >> 3);
  const int kc = swz / 20;
  const int rem = swz % 20;
  const int nt = rem >> 1;
  const int mt = rem & 1;
  const long k0b = (long)kc * (BK * STEPS) * 4;

  const int tid = threadIdx.x;
  const int lane = tid & 63;
  const int wv = tid >> 6;                  // 0..3 -> 2m x 2n wave grid
  const int wm = wv >> 1, wn = wv & 1;
  const int frow = lane & 15;
  const int cbase = (lane >> 4) << 5;       // fp32 byte col of the 8-k group

  // staging geometry: pass q covers rows q*32+(tid>>3), 16 B chunk (tid&7)
  const int srow = tid >> 3;                // 0..31
  const int perm = ((tid & 7) ^ (srow & 7)) << 4;  // inverse-swizzle source
  const char* xbase = (const char*)X + (long)(mt * 128 + srow) * KDIMB + k0b + perm;
  const char* wbase = (const char*)W + (long)(nt * 128 + srow) * KDIMB + k0b + perm;

  // loop-invariant fragment byte offsets: lo and hi XOR'd SEPARATELY
  int aoffl[4], aoffh[4], boffl[4], boffh[4];
#pragma unroll
  for (int i = 0; i < 4; ++i) {
    const int Ra = wm * 64 + i * 16 + frow;
    const int swa = (Ra & 7) << 4;
    aoffl[i] = Ra * 128 + (cbase ^ swa);
    aoffh[i] = Ra * 128 + ((cbase + 16) ^ swa);
    const int Rb = wn * 64 + i * 16 + frow;
    const int swb = (Rb & 7) << 4;
    boffl[i] = ABYTES + Rb * 128 + (cbase ^ swb);
    boffh[i] = ABYTES + Rb * 128 + ((cbase + 16) ^ swb);
  }

  f32x4 acc[4][4];
#pragma unroll
  for (int i = 0; i < 4; ++i)
#pragma unroll
    for (int j = 0; j < 4; ++j) acc[i][j] = (f32x4){0.f, 0.f, 0.f, 0.f};

#define STAGE(buf, t)                                                         \
  {                                                                           \
    const long ko = (long)(t) * (BK * 4);                                     \
    _Pragma("unroll") for (int q = 0; q < 4; ++q)                             \
        gload16(xbase + (long)q * 32 * KDIMB + ko,                            \
                (buf) + q * 4096 + wv * 1024);                                \
    _Pragma("unroll") for (int q = 0; q < 4; ++q)                             \
        gload16(wbase + (long)q * 32 * KDIMB + ko,                            \
                (buf) + ABYTES + q * 4096 + wv * 1024);                       \
  }

#define LOADFRAGS(buf)                                                        \
  f32x4 a0l = *(const f32x4*)((buf) + aoffl[0]),                              \
        a0h = *(const f32x4*)((buf) + aoffh[0]),                              \
        a1l = *(const f32x4*)((buf) + aoffl[1]),                              \
        a1h = *(const f32x4*)((buf) + aoffh[1]),                              \
        a2l = *(const f32x4*)((buf) + aoffl[2]),                              \
        a2h = *(const f32x4*)((buf) + aoffh[2]),                              \
        a3l = *(const f32x4*)((buf) + aoffl[3]),                              \
        a3h = *(const f32x4*)((buf) + aoffh[3]),                              \
        b0l = *(const f32x4*)((buf) + boffl[0]),                              \
        b0h = *(const f32x4*)((buf) + boffh[0]),                              \
        b1l = *(const f32x4*)((buf) + boffl[1]),                              \
        b1h = *(const f32x4*)((buf) + boffh[1]),                              \
        b2l = *(const f32x4*)((buf) + boffl[2]),                              \
        b2h = *(const f32x4*)((buf) + boffh[2]),                              \
        b3l = *(const f32x4*)((buf) + boffl[3]),                              \
        b3h = *(const f32x4*)((buf) + boffh[3]);

#define CVTMFMA()                                                             \
  {                                                                           \
    short8 fa[4], fb[4];                                                      \
    fa[0] = cvt8(a0l, a0h); fa[1] = cvt8(a1l, a1h);                           \
    fa[2] = cvt8(a2l, a2h); fa[3] = cvt8(a3l, a3h);                           \
    fb[0] = cvt8(b0l, b0h); fb[1] = cvt8(b1l, b1h);                           \
    fb[2] = cvt8(b2l, b2h); fb[3] = cvt8(b3l, b3h);                           \
    _Pragma("unroll") for (int i = 0; i < 4; ++i)                             \
        _Pragma("unroll") for (int j = 0; j < 4; ++j)                         \
            acc[i][j] = __builtin_amdgcn_mfma_f32_16x16x32_bf16(              \
                fa[i], fb[j], acc[i][j], 0, 0, 0);                            \
  }

  // prologue: step 0 in flight
  STAGE(smem, 0);

  for (int t = 0; t < STEPS; ++t) {
    char* cbuf = smem + (t & 1) * BUFB;
    char* nbuf = smem + ((t + 1) & 1) * BUFB;
    // own step-t DMA landed (had a full step); then publish across waves.
    asm volatile("s_waitcnt vmcnt(0)" ::: "memory");
    __builtin_amdgcn_s_barrier();           // also: nbuf's t-1 readers done
    __builtin_amdgcn_sched_barrier(0);
    if (t + 1 < STEPS) STAGE(nbuf, t + 1);  // refill HBM queue immediately
    __builtin_amdgcn_sched_barrier(0);
    LOADFRAGS(cbuf);                        // 16x ds_read_b128
    __builtin_amdgcn_s_setprio(1);
    CVTMFMA();                              // compiler inserts counted lgkmcnt
    __builtin_amdgcn_s_setprio(0);
  }

#undef STAGE
#undef LOADFRAGS
#undef CVTMFMA

  // C/D layout: col=lane&15, row=(lane>>4)*4+r  [m89]
  float* Pc = P + (long)kc * PSTRIDE + (long)mt * 128 * HDIM + nt * 128;
  const int rb = wm * 64 + ((lane >> 4) << 2);
  const int cb = wn * 64 + frow;
#pragma unroll
  for (int i = 0; i < 4; ++i)
#pragma unroll
    for (int j = 0; j < 4; ++j) {
      const int col = cb + j * 16;
#pragma unroll
      for (int r = 0; r < 4; ++r)
        Pc[(long)(rb + i * 16 + r) * HDIM + col] = acc[i][j][r];
    }
}

// ---------------------------------------------------------------------------
// K2: S4D kernel table, one thread per (h,l).
// ---------------------------------------------------------------------------
__global__ __launch_bounds__(256) void k_s4d(
    const float* __restrict__ log_dt, const float* __restrict__ lar,
    const float* __restrict__ C, float* __restrict__ ktab) {
  const int idx = blockIdx.x * 256 + threadIdx.x;  // 1280*64
  const int h = idx >> 6, l = idx & 63;
  const float dt = expf(log_dt[h]);
  const float fl = (float)l;
  float acc = 0.f;
#pragma unroll 4
  for (int n = 0; n < 32; ++n) {
    const float A = -expf(lar[h * 32 + n]);
    const float dtA = A * dt;
    const float Cb = C[h * 32 + n] * expm1f(dtA) / A;
    acc += Cb * expf(dtA * fl);
  }
  ktab[idx] = 2.f * acc;
}

// ---------------------------------------------------------------------------
// K3: split-K reduce  U[m][h] = bb[h] + sum_kc P  (full-chip parallel)
// ---------------------------------------------------------------------------
__global__ __launch_bounds__(256) void k_red(
    const float* __restrict__ P, const float* __restrict__ bb,
    float* __restrict__ U) {
  const int idx = blockIdx.x * 256 + threadIdx.x;  // 256*1280
  float s = bb[idx % HDIM];
#pragma unroll
  for (int c = 0; c < KCHUNKS; ++c) s += P[(long)c * PSTRIDE + idx];
  U[idx] = s;
}

// ---------------------------------------------------------------------------
// K4: causal conv at l=63 + D skip + exact GELU (reads tiny U)
// ---------------------------------------------------------------------------
__global__ __launch_bounds__(256) void k_conv(
    const float* __restrict__ U, const float* __restrict__ ktab,
    const float* __restrict__ Dv, float* __restrict__ y63) {
  __shared__ float kt[64 * 65];
  const int t = threadIdx.x;
  const int hw = blockIdx.x * 64;
  for (int i = t; i < 4096; i += 256)
    kt[(i >> 6) * 65 + (i & 63)] = ktab[(hw + (i >> 6)) * 64 + (i & 63)];
  __syncthreads();
  const int hl = t & 63, b = t >> 6;
  const int h = hw + hl;
  float y = 0.f;
  for (int m = 0; m < 64; ++m)
    y += U[(long)(b * 64 + m) * HDIM + h] * kt[hl * 65 + (63 - m)];
  y += Dv[h] * U[(long)(b * 64 + 63) * HDIM + h];
  y63[b * HDIM + h] = 0.5f * y * (1.f + erff(y * 0.70710678118654752f));
}

// ---------------------------------------------------------------------------
// K5: gating z=Wc@y63+bc, last = a*sigmoid(g). One wave per h-row.
// ---------------------------------------------------------------------------
__global__ __launch_bounds__(64) void k_gate(
    const float* __restrict__ y63, const float* __restrict__ Wc,
    const float* __restrict__ bc, float* __restrict__ lastv) {
  const int r = blockIdx.x;       // 0..1279
  const int l = threadIdx.x;      // 0..63
  const float* wa = Wc + (long)r * HDIM;
  const float* wg = Wc + (long)(HDIM + r) * HDIM;
  float sa[4] = {0.f, 0.f, 0.f, 0.f}, sg[4] = {0.f, 0.f, 0.f, 0.f};
#pragma unroll
  for (int seg = 0; seg < 5; ++seg) {
    const int j = seg * 256 + l * 4;
    const f32x4 a4 = *(const f32x4*)(wa + j);
    const f32x4 g4 = *(const f32x4*)(wg + j);
#pragma unroll
    for (int b = 0; b < 4; ++b) {
      const f32x4 yv = *(const f32x4*)(y63 + b * HDIM + j);
      sa[b] += a4.x * yv.x + a4.y * yv.y + a4.z * yv.z + a4.w * yv.w;
      sg[b] += g4.x * yv.x + g4.y * yv.y + g4.z * yv.z + g4.w * yv.w;
    }
  }
#pragma unroll
  for (int off = 32; off; off >>= 1)
#pragma unroll
    for (int b = 0; b < 4; ++b) {
      sa[b] += __shfl_down(sa[b], off);
      sg[b] += __shfl_down(sg[b], off);
    }
  if (l == 0) {
    const float ba = bc[r], bg = bc[HDIM + r];
#pragma unroll
    for (int b = 0; b < 4; ++b) {
      const float za = ba + sa[b], zg = bg + sg[b];
      lastv[b * HDIM + r] = za / (1.f + expf(-zg));
    }
  }
}

// ---------------------------------------------------------------------------
// K6: head  h1 = relu(last @ W1^T + b1); out = h1 @ W2^T + b2
// ---------------------------------------------------------------------------
__global__ __launch_bounds__(64) void k_head(
    const float* __restrict__ lastv, const float* __restrict__ W1,
    const float* __restrict__ b1, const float* __restrict__ W2,
    const float* __restrict__ b2, float* __restrict__ out) {
  __shared__ float ll[HDIM];
  __shared__ float h1[64];
  const int b = blockIdx.x, t = threadIdx.x;
  for (int i = t; i < HDIM; i += 64) ll[i] = lastv[b * HDIM + i];
  __syncthreads();
  {
    const float* w = W1 + t * HDIM;
    float s = b1[t];
    for (int j = 0; j < HDIM; j += 4) {
      const f32x4 wv = *(const f32x4*)(w + j);
      s += wv.x * ll[j] + wv.y * ll[j + 1] + wv.z * ll[j + 2] + wv.w * ll[j + 3];
    }
    h1[t] = fmaxf(s, 0.f);
  }
  __syncthreads();
  if (t < 60) {
    const float* w = W2 + t * 64;
    float o = b2[t];
#pragma unroll
    for (int r = 0; r < 64; ++r) o += w[r] * h1[r];
    out[b * 60 + t] = o;
  }
}

extern "C" void kernel_launch(void* const* d_in, const int* in_sizes, int n_in,
                              void* d_out, int out_size, void* d_ws, size_t ws_size,
                              hipStream_t stream) {
  const float* x   = (const float*)d_in[0];
  const float* Wb  = (const float*)d_in[1];
  const float* bb  = (const float*)d_in[2];
  const float* ldt = (const float*)d_in[3];
  const float* C   = (const float*)d_in[4];
  const float* lar = (const float*)d_in[5];
  const float* Dv  = (const float*)d_in[6];
  const float* Wc  = (const float*)d_in[7];
  const float* bc  = (const float*)d_in[8];
  const float* W1  = (const float*)d_in[9];
  const float* b1  = (const float*)d_in[10];
  const float* W2  = (const float*)d_in[11];
  const float* b2  = (const float*)d_in[12];
  float* out = (float*)d_out;

  float* P     = (float*)d_ws;                     // 24*256*1280 f32 = 31.5 MB
  float* ktab  = P + (long)KCHUNKS * PSTRIDE;      // 1280*64
  float* U     = ktab + HDIM * 64;                 // 256*1280
  float* y63   = U + PSTRIDE;                      // 4*1280
  float* lastv = y63 + 4 * HDIM;                   // 4*1280

  (void)hipFuncSetAttribute(reinterpret_cast<const void*>(k_gemm),
                            hipFuncAttributeMaxDynamicSharedMemorySize,
                            2 * BUFB);

  k_s4d<<<320, 256, 0, stream>>>(ldt, lar, C, ktab);
  k_gemm<<<NT_TILES * MT_TILES * KCHUNKS, 256, 2 * BUFB, stream>>>(x, Wb, P);
  k_red<<<PSTRIDE / 256, 256, 0, stream>>>(P, bb, U);
  k_conv<<<20, 256, 0, stream>>>(U, ktab, Dv, y63);
  k_gate<<<HDIM, 64, 0, stream>>>(y63, Wc, bc, lastv);
  k_head<<<4, 64, 0, stream>>>(lastv, W1, b1, W2, b2, out);
}

// Round 18
// 296.041 us; speedup vs baseline: 2.9230x; 1.1646x over previous
//
#include <hip/hip_runtime.h>
#include <hip/hip_bf16.h>
#include <math.h>

typedef __attribute__((ext_vector_type(8))) short short8;
typedef __attribute__((ext_vector_type(4))) float f32x4;
typedef __attribute__((ext_vector_type(4))) unsigned int u32x4;

#define KDIM 150528
#define KDIMB ((long)KDIM * 4)
#define NT_TILES 10
#define KCHUNKS 24
#define STEPS 196         // 6272 / 32
#define BK 32             // fp32 -> 128 B LDS rows
#define HDIM 1280
#define MDIM 256
#define PSTRIDE (MDIM * HDIM)
#define ABYTES 32768      // A: 256 rows * 128 B
#define BUFB 49152        // + B: 128 rows * 128 B
// LDS: 3 buffers * 48 KB = 144 KB -> 1 block/CU

// packed fp32x2 -> bf16x2 RNE, single HW instruction (no builtin on gfx950)
__device__ __forceinline__ unsigned int pk2(float a, float b) {
  unsigned int r;
  asm("v_cvt_pk_bf16_f32 %0, %1, %2" : "=v"(r) : "v"(a), "v"(b));
  return r;
}

// async global->LDS DMA, 16 B per lane, zero VGPR cost
__device__ __forceinline__ void gload16(const void* g, const char* l) {
  __builtin_amdgcn_global_load_lds(
      (const __attribute__((address_space(1))) unsigned int*)g,
      (__attribute__((address_space(3))) unsigned int*)l, 16, 0, 0);
}

__device__ __forceinline__ short8 cvt8(f32x4 lo, f32x4 hi) {
  union { u32x4 u; short8 s; } c;
  c.u = (u32x4){pk2(lo.x, lo.y), pk2(lo.z, lo.w), pk2(hi.x, hi.y), pk2(hi.z, hi.w)};
  return c.s;
}

// ---------------------------------------------------------------------------
// K1: split-K GEMM  P[kc][m][n] += X[m,k]*W[n,k] over k-chunk kc.
// Tile 256x128, BK=32, 512 thr (8 waves 4m x 2n, wave tile 64x64, acc 4x4).
// PROVEN BEST (R12, 295.9 us; reverted after R13-R17 alternatives all lost):
// fp32 DMA staging (global_load_lds, zero VGPR), 3 rotating LDS buffers,
// depth-2 prefetch, counted s_waitcnt vmcnt(6) + ONE raw s_barrier per step
// (vmcnt NEVER drains to 0 in the loop), ds_read-first phase order, T5
// setprio around the cvt+MFMA cluster. lo/hi frag offsets XOR'd separately.
// ---------------------------------------------------------------------------
__global__ __launch_bounds__(512, 2) void k_gemm(
    const float* __restrict__ X, const float* __restrict__ W,
    float* __restrict__ P) {
  extern __shared__ char smem[];
  // XCD-chunked swizzle (240 % 8 == 0): each XCD owns 3 kc x 10 nt blocks
  const int swz = (blockIdx.x & 7) * 30 + (blockIdx.x >> 3);
  const int kc = swz / 10;
  const int nt = swz % 10;
  const long k0b = (long)kc * (BK * STEPS) * 4;

  const int tid = threadIdx.x;
  const int lane = tid & 63;
  const int wv = tid >> 6;                  // 0..7 -> 4m x 2n wave grid
  const int wm = wv >> 1, wn = wv & 1;
  const int frow = lane & 15;
  const int cbase = (lane >> 4) << 5;       // fp32 byte col of the 8-k group

  // staging geometry: thread covers row (q*64 + tid>>3), 16 B chunk (tid&7)
  const int srow = tid >> 3;                // 0..63
  const int perm = ((tid & 7) ^ (srow & 7)) << 4;  // inverse-swizzle source
  const char* xbase = (const char*)X + (long)srow * KDIMB + k0b + perm;
  const char* wbase = (const char*)W + (long)(nt * 128 + srow) * KDIMB + k0b + perm;

  // loop-invariant fragment byte offsets: lo and hi XOR'd SEPARATELY
  int aoffl[4], aoffh[4], boffl[4], boffh[4];
#pragma unroll
  for (int i = 0; i < 4; ++i) {
    const int Ra = wm * 64 + i * 16 + frow;
    const int swa = (Ra & 7) << 4;
    aoffl[i] = Ra * 128 + (cbase ^ swa);
    aoffh[i] = Ra * 128 + ((cbase + 16) ^ swa);
    const int Rb = wn * 64 + i * 16 + frow;
    const int swb = (Rb & 7) << 4;
    boffl[i] = ABYTES + Rb * 128 + (cbase ^ swb);
    boffh[i] = ABYTES + Rb * 128 + ((cbase + 16) ^ swb);
  }

  f32x4 acc[4][4];
#pragma unroll
  for (int i = 0; i < 4; ++i)
#pragma unroll
    for (int j = 0; j < 4; ++j) acc[i][j] = (f32x4){0.f, 0.f, 0.f, 0.f};

#define STAGE(buf, t)                                                         \
  {                                                                           \
    const long ko = (long)(t) * (BK * 4);                                     \
    _Pragma("unroll") for (int q = 0; q < 4; ++q)                             \
        gload16(xbase + (long)q * 64 * KDIMB + ko,                            \
                (buf) + q * 8192 + wv * 1024);                                \
    _Pragma("unroll") for (int q = 0; q < 2; ++q)                             \
        gload16(wbase + (long)q * 64 * KDIMB + ko,                            \
                (buf) + ABYTES + q * 8192 + wv * 1024);                       \
  }

  // phase 1: issue all 16 ds_reads (raw fp32 halves, named vars)
#define LOADFRAGS(buf)                                                        \
  f32x4 a0l = *(const f32x4*)((buf) + aoffl[0]),                              \
        a0h = *(const f32x4*)((buf) + aoffh[0]),                              \
        a1l = *(const f32x4*)((buf) + aoffl[1]),                              \
        a1h = *(const f32x4*)((buf) + aoffh[1]),                              \
        a2l = *(const f32x4*)((buf) + aoffl[2]),                              \
        a2h = *(const f32x4*)((buf) + aoffh[2]),                              \
        a3l = *(const f32x4*)((buf) + aoffl[3]),                              \
        a3h = *(const f32x4*)((buf) + aoffh[3]),                              \
        b0l = *(const f32x4*)((buf) + boffl[0]),                              \
        b0h = *(const f32x4*)((buf) + boffh[0]),                              \
        b1l = *(const f32x4*)((buf) + boffl[1]),                              \
        b1h = *(const f32x4*)((buf) + boffh[1]),                              \
        b2l = *(const f32x4*)((buf) + boffl[2]),                              \
        b2h = *(const f32x4*)((buf) + boffh[2]),                              \
        b3l = *(const f32x4*)((buf) + boffl[3]),                              \
        b3h = *(const f32x4*)((buf) + boffh[3]);

  // phase 3: convert + 16 MFMA (setprio-wrapped by caller)
#define CVTMFMA()                                                             \
  {                                                                           \
    short8 fa[4], fb[4];                                                      \
    fa[0] = cvt8(a0l, a0h); fa[1] = cvt8(a1l, a1h);                           \
    fa[2] = cvt8(a2l, a2h); fa[3] = cvt8(a3l, a3h);                           \
    fb[0] = cvt8(b0l, b0h); fb[1] = cvt8(b1l, b1h);                           \
    fb[2] = cvt8(b2l, b2h); fb[3] = cvt8(b3l, b3h);                           \
    _Pragma("unroll") for (int i = 0; i < 4; ++i)                             \
        _Pragma("unroll") for (int j = 0; j < 4; ++j)                         \
            acc[i][j] = __builtin_amdgcn_mfma_f32_16x16x32_bf16(              \
                fa[i], fb[j], acc[i][j], 0, 0, 0);                            \
  }

  char* b_cur = smem;
  char* b_nxt = smem + BUFB;
  char* b_stg = smem + 2 * BUFB;

  // prologue: steps 0 and 1 in flight (12 outstanding VMEM ops per wave)
  STAGE(b_cur, 0);
  STAGE(b_nxt, 1);

  for (int t = 0; t < STEPS - 1; ++t) {
    // counted wait: 12 outstanding -> oldest 6 (step t) landed. NOT vmcnt(0).
    asm volatile("s_waitcnt vmcnt(6)" ::: "memory");
    __builtin_amdgcn_s_barrier();           // all waves' step-t loads visible
    __builtin_amdgcn_sched_barrier(0);
    LOADFRAGS(b_cur);                       // 16x ds_read_b128 issued first
    __builtin_amdgcn_sched_barrier(0);
    if (t + 2 < STEPS) STAGE(b_stg, t + 2); // VMEM issue overlaps ds latency
    __builtin_amdgcn_sched_barrier(0);
    __builtin_amdgcn_s_setprio(1);
    CVTMFMA();                              // compiler inserts counted lgkmcnt
    __builtin_amdgcn_s_setprio(0);
    char* tmp = b_cur; b_cur = b_nxt; b_nxt = b_stg; b_stg = tmp;
  }
  // final step: drain everything
  asm volatile("s_waitcnt vmcnt(0)" ::: "memory");
  __builtin_amdgcn_s_barrier();
  __builtin_amdgcn_sched_barrier(0);
  {
    LOADFRAGS(b_cur);
    CVTMFMA();
  }

#undef STAGE
#undef LOADFRAGS
#undef CVTMFMA

  // C/D layout: col=lane&15, row=(lane>>4)*4+r  [m89]
  float* Pc = P + (long)kc * PSTRIDE + nt * 128;
  const int rb = wm * 64 + ((lane >> 4) << 2);
  const int cb = wn * 64 + frow;
#pragma unroll
  for (int i = 0; i < 4; ++i)
#pragma unroll
    for (int j = 0; j < 4; ++j) {
      const int col = cb + j * 16;
#pragma unroll
      for (int r = 0; r < 4; ++r)
        Pc[(long)(rb + i * 16 + r) * HDIM + col] = acc[i][j][r];
    }
}

// ---------------------------------------------------------------------------
// K2: S4D kernel table, one thread per (h,l).
// ---------------------------------------------------------------------------
__global__ __launch_bounds__(256) void k_s4d(
    const float* __restrict__ log_dt, const float* __restrict__ lar,
    const float* __restrict__ C, float* __restrict__ ktab) {
  const int idx = blockIdx.x * 256 + threadIdx.x;  // 1280*64
  const int h = idx >> 6, l = idx & 63;
  const float dt = expf(log_dt[h]);
  const float fl = (float)l;
  float acc = 0.f;
#pragma unroll 4
  for (int n = 0; n < 32; ++n) {
    const float A = -expf(lar[h * 32 + n]);
    const float dtA = A * dt;
    const float Cb = C[h * 32 + n] * expm1f(dtA) / A;
    acc += Cb * expf(dtA * fl);
  }
  ktab[idx] = 2.f * acc;
}

// ---------------------------------------------------------------------------
// K3: split-K reduce  U[m][h] = bb[h] + sum_kc P  (full-chip parallel)
// ---------------------------------------------------------------------------
__global__ __launch_bounds__(256) void k_red(
    const float* __restrict__ P, const float* __restrict__ bb,
    float* __restrict__ U) {
  const int idx = blockIdx.x * 256 + threadIdx.x;  // 256*1280
  float s = bb[idx % HDIM];
#pragma unroll
  for (int c = 0; c < KCHUNKS; ++c) s += P[(long)c * PSTRIDE + idx];
  U[idx] = s;
}

// ---------------------------------------------------------------------------
// K4: causal conv at l=63 + D skip + exact GELU (reads tiny U)
// ---------------------------------------------------------------------------
__global__ __launch_bounds__(256) void k_conv(
    const float* __restrict__ U, const float* __restrict__ ktab,
    const float* __restrict__ Dv, float* __restrict__ y63) {
  __shared__ float kt[64 * 65];
  const int t = threadIdx.x;
  const int hw = blockIdx.x * 64;
  for (int i = t; i < 4096; i += 256)
    kt[(i >> 6) * 65 + (i & 63)] = ktab[(hw + (i >> 6)) * 64 + (i & 63)];
  __syncthreads();
  const int hl = t & 63, b = t >> 6;
  const int h = hw + hl;
  float y = 0.f;
  for (int m = 0; m < 64; ++m)
    y += U[(long)(b * 64 + m) * HDIM + h] * kt[hl * 65 + (63 - m)];
  y += Dv[h] * U[(long)(b * 64 + 63) * HDIM + h];
  y63[b * HDIM + h] = 0.5f * y * (1.f + erff(y * 0.70710678118654752f));
}

// ---------------------------------------------------------------------------
// K5: gating z=Wc@y63+bc, last = a*sigmoid(g). One wave per h-row.
// ---------------------------------------------------------------------------
__global__ __launch_bounds__(64) void k_gate(
    const float* __restrict__ y63, const float* __restrict__ Wc,
    const float* __restrict__ bc, float* __restrict__ lastv) {
  const int r = blockIdx.x;       // 0..1279
  const int l = threadIdx.x;      // 0..63
  const float* wa = Wc + (long)r * HDIM;
  const float* wg = Wc + (long)(HDIM + r) * HDIM;
  float sa[4] = {0.f, 0.f, 0.f, 0.f}, sg[4] = {0.f, 0.f, 0.f, 0.f};
#pragma unroll
  for (int seg = 0; seg < 5; ++seg) {
    const int j = seg * 256 + l * 4;
    const f32x4 a4 = *(const f32x4*)(wa + j);
    const f32x4 g4 = *(const f32x4*)(wg + j);
#pragma unroll
    for (int b = 0; b < 4; ++b) {
      const f32x4 yv = *(const f32x4*)(y63 + b * HDIM + j);
      sa[b] += a4.x * yv.x + a4.y * yv.y + a4.z * yv.z + a4.w * yv.w;
      sg[b] += g4.x * yv.x + g4.y * yv.y + g4.z * yv.z + g4.w * yv.w;
    }
  }
#pragma unroll
  for (int off = 32; off; off >>= 1)
#pragma unroll
    for (int b = 0; b < 4; ++b) {
      sa[b] += __shfl_down(sa[b], off);
      sg[b] += __shfl_down(sg[b], off);
    }
  if (l == 0) {
    const float ba = bc[r], bg = bc[HDIM + r];
#pragma unroll
    for (int b = 0; b < 4; ++b) {
      const float za = ba + sa[b], zg = bg + sg[b];
      lastv[b * HDIM + r] = za / (1.f + expf(-zg));
    }
  }
}

// ---------------------------------------------------------------------------
// K6: head  h1 = relu(last @ W1^T + b1); out = h1 @ W2^T + b2
// ---------------------------------------------------------------------------
__global__ __launch_bounds__(64) void k_head(
    const float* __restrict__ lastv, const float* __restrict__ W1,
    const float* __restrict__ b1, const float* __restrict__ W2,
    const float* __restrict__ b2, float* __restrict__ out) {
  __shared__ float ll[HDIM];
  __shared__ float h1[64];
  const int b = blockIdx.x, t = threadIdx.x;
  for (int i = t; i < HDIM; i += 64) ll[i] = lastv[b * HDIM + i];
  __syncthreads();
  {
    const float* w = W1 + t * HDIM;
    float s = b1[t];
    for (int j = 0; j < HDIM; j += 4) {
      const f32x4 wv = *(const f32x4*)(w + j);
      s += wv.x * ll[j] + wv.y * ll[j + 1] + wv.z * ll[j + 2] + wv.w * ll[j + 3];
    }
    h1[t] = fmaxf(s, 0.f);
  }
  __syncthreads();
  if (t < 60) {
    const float* w = W2 + t * 64;
    float o = b2[t];
#pragma unroll
    for (int r = 0; r < 64; ++r) o += w[r] * h1[r];
    out[b * 60 + t] = o;
  }
}

extern "C" void kernel_launch(void* const* d_in, const int* in_sizes, int n_in,
                              void* d_out, int out_size, void* d_ws, size_t ws_size,
                              hipStream_t stream) {
  const float* x   = (const float*)d_in[0];
  const float* Wb  = (const float*)d_in[1];
  const float* bb  = (const float*)d_in[2];
  const float* ldt = (const float*)d_in[3];
  const float* C   = (const float*)d_in[4];
  const float* lar = (const float*)d_in[5];
  const float* Dv  = (const float*)d_in[6];
  const float* Wc  = (const float*)d_in[7];
  const float* bc  = (const float*)d_in[8];
  const float* W1  = (const float*)d_in[9];
  const float* b1  = (const float*)d_in[10];
  const float* W2  = (const float*)d_in[11];
  const float* b2  = (const float*)d_in[12];
  float* out = (float*)d_out;

  float* P     = (float*)d_ws;                     // 24*256*1280 f32 = 31.5 MB
  float* ktab  = P + (long)KCHUNKS * PSTRIDE;      // 1280*64
  float* U     = ktab + HDIM * 64;                 // 256*1280
  float* y63   = U + PSTRIDE;                      // 4*1280
  float* lastv = y63 + 4 * HDIM;                   // 4*1280

  (void)hipFuncSetAttribute(reinterpret_cast<const void*>(k_gemm),
                            hipFuncAttributeMaxDynamicSharedMemorySize,
                            3 * BUFB);

  k_s4d<<<320, 256, 0, stream>>>(ldt, lar, C, ktab);
  k_gemm<<<NT_TILES * KCHUNKS, 512, 3 * BUFB, stream>>>(x, Wb, P);
  k_red<<<PSTRIDE / 256, 256, 0, stream>>>(P, bb, U);
  k_conv<<<20, 256, 0, stream>>>(U, ktab, Dv, y63);
  k_gate<<<HDIM, 64, 0, stream>>>(y63, Wc, bc, lastv);
  k_head<<<4, 64, 0, stream>>>(lastv, W1, b1, W2, b2, out);
}